// Round 1
// baseline (440.738 us; speedup 1.0000x reference)
//
#include <hip/hip_runtime.h>
#include <stdint.h>

// CMAALayer fused kernel, MI355X gfx950. Round 4.
// Redesign vs round 3 (540.6 us):
//   - RT 32 -> 64 rows/block, 512 threads (8 waves), 2048 blocks, 1 block/CU.
//     Each weight fragment now feeds 4 row-tiles -> weight L2 traffic halved.
//   - V_eff = sigmoid(R)*V fused into the QKVR epilogue: waves 4..7 compute
//     BOTH V and R for the same 64-col slice, so sigmoid runs once per element
//     (was 3x, once per consumer) and R is never stored to LDS.
//   - Single full-width attention pass: 512 threads = 64 rows x 8 heads, all
//     threads active (was 128 threads x 2 phases). PV has no transcendentals.
//   - sAO aliased over dead Q region of sQK; sY(fp32) aliased over sQK.
//     LDS: sX 33.8KB + sQK 97KB = 130KB.
// K0 (weight fp32->bf16 conversion) unchanged.

#define D_DIM   256
#define H_NUM   8
#define DH      32
#define RT      64
#define NTHR    512
#define ROWS_TOT 131072
#define Y_SZ    33554432          // 131072*256
#define SCALE_F 0.17677669529663687f
#define W_ELEMS 65536             // 256*256 per matrix
#define WS_NEED (5 * W_ELEMS * 2) // bytes for bf16 weight copy

#define SX_LD   264   // shorts
#define SQK_LD  776   // shorts per row: [Q 0..255 | K 256..511 | Veff 512..767 | pad]
#define KOFF    256
#define VOFF    512
#define SY_LD   260   // floats (aliases sQK storage)

typedef __attribute__((ext_vector_type(8))) short bf16x8;
typedef __attribute__((ext_vector_type(4))) float f32x4;

__device__ __forceinline__ float b2f(uint16_t s) {
    union { uint32_t u; float f; } c; c.u = ((uint32_t)s) << 16; return c.f;
}
__device__ __forceinline__ uint16_t f2b(float f) {
    union { float f; uint32_t u; } c; c.f = f;
    return (uint16_t)((c.u + 0x7fffu + ((c.u >> 16) & 1u)) >> 16);
}
__device__ __forceinline__ bf16x8 cvt8(const float* p) {
    const float4 a = *(const float4*)p;
    const float4 b = *(const float4*)(p + 4);
    bf16x8 r;
    r[0] = (short)f2b(a.x); r[1] = (short)f2b(a.y);
    r[2] = (short)f2b(a.z); r[3] = (short)f2b(a.w);
    r[4] = (short)f2b(b.x); r[5] = (short)f2b(b.y);
    r[6] = (short)f2b(b.z); r[7] = (short)f2b(b.w);
    return r;
}

// ---------------- K0: weight fp32 -> bf16 conversion ----------------
__global__ __launch_bounds__(256)
void conv_weights(const float* __restrict__ Wq, const float* __restrict__ Wk,
                  const float* __restrict__ Wv, const float* __restrict__ Wr,
                  const float* __restrict__ Wo, uint16_t* __restrict__ dst)
{
    const int m = blockIdx.x >> 6;                 // matrix id 0..4
    const float* src = (m == 0) ? Wq : (m == 1) ? Wk : (m == 2) ? Wv
                     : (m == 3) ? Wr : Wo;
    const int base = (blockIdx.x & 63) * 1024 + threadIdx.x * 4;
    const float4 v = *(const float4*)&src[base];
    uint2 pk;
    pk.x = (uint32_t)f2b(v.x) | ((uint32_t)f2b(v.y) << 16);
    pk.y = (uint32_t)f2b(v.z) | ((uint32_t)f2b(v.w) << 16);
    *(uint2*)&dst[(size_t)m * W_ELEMS + base] = pk;
}

// ---------------- K1: fused layer ----------------
template<bool WBF16>
__global__ __launch_bounds__(NTHR, 2)
void cmaa_fused(const float* __restrict__ tok,
                const float* __restrict__ Wq, const float* __restrict__ Wk,
                const float* __restrict__ Wv, const float* __restrict__ Wr,
                const float* __restrict__ Wo,
                const uint16_t* __restrict__ wbf,
                const float* __restrict__ lng, const float* __restrict__ lnb,
                float* __restrict__ outp)
{
    __shared__ __align__(16) uint16_t sX [RT * SX_LD];    // 33792 B
    __shared__ __align__(16) uint16_t sQK[RT * SQK_LD];   // 99328 B; also sY fp32

    const int tid  = threadIdx.x;
    const int wv   = tid >> 6;        // wave 0..7
    const int lane = tid & 63;
    const int l15  = lane & 15;
    const int quad = lane >> 4;
    const int R0   = blockIdx.x * RT;

    // ---------------- stage 0: X tile -> LDS (bf16) ----------------
    {
        const float* g = tok + (size_t)R0 * D_DIM;
        #pragma unroll
        for (int t = tid; t < RT * (D_DIM / 8); t += NTHR) {
            const int row = t >> 5, c = t & 31;
            *(bf16x8*)&sX[row * SX_LD + c * 8] = cvt8(&g[row * D_DIM + c * 8]);
        }
    }
    __syncthreads();

    // ---------------- QKVR GEMM ----------------
    // waves 0..3: Q (acc[0]) and K (acc[1]), col slice (wv&3)*64 .. +64
    // waves 4..7: V (acc[0]) and R (acc[1]), same col slices
    {
        const int colbase = (wv & 3) * 64;
        const float*    WF0 = (wv < 4) ? Wq : Wv;
        const float*    WF1 = (wv < 4) ? Wk : Wr;
        const uint16_t* WB0 = wbf + (size_t)((wv < 4) ? 0 : 2) * W_ELEMS;
        const uint16_t* WB1 = WB0 + W_ELEMS;

        f32x4 acc[2][4][4];
        #pragma unroll
        for (int m = 0; m < 2; ++m)
            #pragma unroll
            for (int mt = 0; mt < 4; ++mt)
                #pragma unroll
                for (int nt = 0; nt < 4; ++nt)
                    acc[m][mt][nt] = (f32x4){0.f, 0.f, 0.f, 0.f};

        #pragma unroll
        for (int kk = 0; kk < 8; ++kk) {
            const int k0 = kk * 32;
            bf16x8 a[4];
            #pragma unroll
            for (int mt = 0; mt < 4; ++mt)
                a[mt] = *(const bf16x8*)&sX[(mt * 16 + l15) * SX_LD + k0 + quad * 8];

            bf16x8 bw[4];
            #pragma unroll
            for (int nt = 0; nt < 4; ++nt) {
                const int wrow = colbase + nt * 16 + l15;
                if constexpr (WBF16)
                    bw[nt] = *(const bf16x8*)&WB0[(size_t)wrow * D_DIM + k0 + quad * 8];
                else
                    bw[nt] = cvt8(&WF0[(size_t)wrow * D_DIM + k0 + quad * 8]);
            }
            #pragma unroll
            for (int nt = 0; nt < 4; ++nt)
                #pragma unroll
                for (int mt = 0; mt < 4; ++mt)
                    acc[0][mt][nt] = __builtin_amdgcn_mfma_f32_16x16x32_bf16(a[mt], bw[nt], acc[0][mt][nt], 0, 0, 0);

            #pragma unroll
            for (int nt = 0; nt < 4; ++nt) {
                const int wrow = colbase + nt * 16 + l15;
                if constexpr (WBF16)
                    bw[nt] = *(const bf16x8*)&WB1[(size_t)wrow * D_DIM + k0 + quad * 8];
                else
                    bw[nt] = cvt8(&WF1[(size_t)wrow * D_DIM + k0 + quad * 8]);
            }
            #pragma unroll
            for (int nt = 0; nt < 4; ++nt)
                #pragma unroll
                for (int mt = 0; mt < 4; ++mt)
                    acc[1][mt][nt] = __builtin_amdgcn_mfma_f32_16x16x32_bf16(a[mt], bw[nt], acc[1][mt][nt], 0, 0, 0);
        }

        // epilogue. C layout: col=lane&15, row=quad*4+reg
        if (wv < 4) {
            #pragma unroll
            for (int mt = 0; mt < 4; ++mt)
                #pragma unroll
                for (int nt = 0; nt < 4; ++nt)
                    #pragma unroll
                    for (int r = 0; r < 4; ++r) {
                        const int row = mt * 16 + quad * 4 + r;
                        const int col = colbase + nt * 16 + l15;
                        sQK[row * SQK_LD + col]        = f2b(acc[0][mt][nt][r]);   // Q
                        sQK[row * SQK_LD + KOFF + col] = f2b(acc[1][mt][nt][r]);   // K
                    }
        } else {
            #pragma unroll
            for (int mt = 0; mt < 4; ++mt)
                #pragma unroll
                for (int nt = 0; nt < 4; ++nt)
                    #pragma unroll
                    for (int r = 0; r < 4; ++r) {
                        const int row = mt * 16 + quad * 4 + r;
                        const int col = colbase + nt * 16 + l15;
                        const float vv = acc[0][mt][nt][r];
                        const float rr = acc[1][mt][nt][r];
                        const float sig = 1.f / (1.f + __expf(-rr));
                        sQK[row * SQK_LD + VOFF + col] = f2b(vv * sig);            // V_eff
                    }
        }
    }
    __syncthreads();

    // ---------------- attention: 512 threads = 64 rows x 8 heads ----------------
    {
        const int r  = tid >> 3;
        const int h  = tid & 7;
        const int gr = R0 + r;
        const int i  = r & 3;
        const int rb = r & ~3;
        int rn[3];
        #pragma unroll
        for (int l = 0; l < 3; ++l) { const int jj = l + (l >= i); rn[l] = rb + jj; }

        float q[DH];
        #pragma unroll
        for (int t = 0; t < 4; ++t) {
            const bf16x8 v = *(const bf16x8*)&sQK[r * SQK_LD + h * DH + t * 8];
            #pragma unroll
            for (int j = 0; j < 8; ++j) q[t * 8 + j] = b2f((uint16_t)v[j]);
        }

        float sc[3];
        #pragma unroll
        for (int l = 0; l < 3; ++l) {
            float s = 0.f;
            #pragma unroll
            for (int t = 0; t < 4; ++t) {
                const bf16x8 v = *(const bf16x8*)&sQK[rn[l] * SQK_LD + KOFF + h * DH + t * 8];
                #pragma unroll
                for (int j = 0; j < 8; ++j) s += q[t * 8 + j] * b2f((uint16_t)v[j]);
            }
            sc[l] = s * SCALE_F;
        }
        const float mx = fmaxf(sc[0], fmaxf(sc[1], sc[2]));
        const float e0 = __expf(sc[0] - mx), e1 = __expf(sc[1] - mx), e2 = __expf(sc[2] - mx);
        const float inv = 1.f / (e0 + e1 + e2);
        const float al[3] = { e0 * inv, e1 * inv, e2 * inv };

        float* ap = outp + Y_SZ + ((size_t)gr * H_NUM + h) * 3;
        ap[0] = al[0]; ap[1] = al[1]; ap[2] = al[2];

        __syncthreads();   // all Q/K reads done before AO overwrites Q region

        #pragma unroll
        for (int t = 0; t < 4; ++t) {
            float o[8] = {0.f,0.f,0.f,0.f,0.f,0.f,0.f,0.f};
            #pragma unroll
            for (int l = 0; l < 3; ++l) {
                const bf16x8 vv = *(const bf16x8*)&sQK[rn[l] * SQK_LD + VOFF + h * DH + t * 8];
                #pragma unroll
                for (int j = 0; j < 8; ++j) o[j] += al[l] * b2f((uint16_t)vv[j]);
            }
            bf16x8 pk;
            #pragma unroll
            for (int j = 0; j < 8; ++j) pk[j] = (short)f2b(o[j]);
            *(bf16x8*)&sQK[r * SQK_LD + h * DH + t * 8] = pk;   // AO over dead Q
        }
    }
    __syncthreads();

    // ---------------- AO @ Wo^T + residual -> sY(fp32) ----------------
    {
        f32x4 acc3[4][2];
        #pragma unroll
        for (int mt = 0; mt < 4; ++mt)
            #pragma unroll
            for (int nt = 0; nt < 2; ++nt)
                acc3[mt][nt] = (f32x4){0.f, 0.f, 0.f, 0.f};

        const uint16_t* WoB = wbf + (size_t)4 * W_ELEMS;
        #pragma unroll
        for (int kk = 0; kk < 8; ++kk) {
            const int k0 = kk * 32;
            bf16x8 a[4];
            #pragma unroll
            for (int mt = 0; mt < 4; ++mt)
                a[mt] = *(const bf16x8*)&sQK[(mt * 16 + l15) * SQK_LD + k0 + quad * 8];
            bf16x8 bw[2];
            #pragma unroll
            for (int nt = 0; nt < 2; ++nt) {
                const int wrow = wv * 32 + nt * 16 + l15;
                if constexpr (WBF16)
                    bw[nt] = *(const bf16x8*)&WoB[(size_t)wrow * D_DIM + k0 + quad * 8];
                else
                    bw[nt] = cvt8(&Wo[(size_t)wrow * D_DIM + k0 + quad * 8]);
            }
            #pragma unroll
            for (int nt = 0; nt < 2; ++nt)
                #pragma unroll
                for (int mt = 0; mt < 4; ++mt)
                    acc3[mt][nt] = __builtin_amdgcn_mfma_f32_16x16x32_bf16(a[mt], bw[nt], acc3[mt][nt], 0, 0, 0);
        }
        __syncthreads();   // all AO reads done before sY aliases sQK

        float* sY = (float*)sQK;
        #pragma unroll
        for (int mt = 0; mt < 4; ++mt)
            #pragma unroll
            for (int nt = 0; nt < 2; ++nt)
                #pragma unroll
                for (int r = 0; r < 4; ++r) {
                    const int row = mt * 16 + quad * 4 + r;
                    const int col = wv * 32 + nt * 16 + l15;
                    sY[row * SY_LD + col] = acc3[mt][nt][r] + b2f(sX[row * SX_LD + col]);
                }
    }
    __syncthreads();

    // ---------------- two-pass LayerNorm + store y ----------------
    {
        const float* sY = (const float*)sQK;
        const int row = tid >> 3;   // 64 rows x 8 lanes
        const int sub = tid & 7;
        float vals[32];
        float s = 0.f;
        #pragma unroll
        for (int j = 0; j < 8; ++j) {
            const float4 v = *(const float4*)&sY[row * SY_LD + j * 32 + sub * 4];
            vals[j*4+0] = v.x; vals[j*4+1] = v.y; vals[j*4+2] = v.z; vals[j*4+3] = v.w;
            s += v.x + v.y + v.z + v.w;
        }
        s += __shfl_xor(s, 1); s += __shfl_xor(s, 2); s += __shfl_xor(s, 4);
        const float mean = s * (1.f / 256.f);
        float s2 = 0.f;
        #pragma unroll
        for (int j = 0; j < 32; ++j) { const float d = vals[j] - mean; s2 += d * d; }
        s2 += __shfl_xor(s2, 1); s2 += __shfl_xor(s2, 2); s2 += __shfl_xor(s2, 4);
        const float var  = fmaxf(s2 * (1.f / 256.f), 0.f);
        const float rstd = rsqrtf(var + 1e-5f);

        float* orow = outp + (size_t)(R0 + row) * D_DIM;
        #pragma unroll
        for (int j = 0; j < 8; ++j) {
            const int col = j * 32 + sub * 4;
            const float4 g4 = *(const float4*)&lng[col];
            const float4 b4 = *(const float4*)&lnb[col];
            float4 o4;
            o4.x = (vals[j*4+0] - mean) * rstd * g4.x + b4.x;
            o4.y = (vals[j*4+1] - mean) * rstd * g4.y + b4.y;
            o4.z = (vals[j*4+2] - mean) * rstd * g4.z + b4.z;
            o4.w = (vals[j*4+3] - mean) * rstd * g4.w + b4.w;
            *(float4*)&orow[col] = o4;
        }
    }
}

extern "C" void kernel_launch(void* const* d_in, const int* in_sizes, int n_in,
                              void* d_out, int out_size, void* d_ws, size_t ws_size,
                              hipStream_t stream) {
    (void)in_sizes; (void)n_in; (void)out_size;
    const float* tok = (const float*)d_in[0];
    const float* Wq  = (const float*)d_in[1];
    const float* Wk  = (const float*)d_in[2];
    const float* Wv  = (const float*)d_in[3];
    const float* Wr  = (const float*)d_in[4];
    const float* Wo  = (const float*)d_in[5];
    const float* lng = (const float*)d_in[6];
    const float* lnb = (const float*)d_in[7];
    float* outp = (float*)d_out;
    uint16_t* wbf = (uint16_t*)d_ws;

    dim3 grid(ROWS_TOT / RT), block(NTHR);
    if (ws_size >= (size_t)WS_NEED) {
        conv_weights<<<dim3(320), dim3(256), 0, stream>>>(Wq, Wk, Wv, Wr, Wo, wbf);
        cmaa_fused<true><<<grid, block, 0, stream>>>(
            tok, Wq, Wk, Wv, Wr, Wo, wbf, lng, lnb, outp);
    } else {
        cmaa_fused<false><<<grid, block, 0, stream>>>(
            tok, Wq, Wk, Wv, Wr, Wo, wbf, lng, lnb, outp);
    }
}

// Round 2
// 432.796 us; speedup vs baseline: 1.0183x; 1.0183x over previous
//
#include <hip/hip_runtime.h>
#include <stdint.h>

// CMAALayer fused kernel, MI355X gfx950. Round 5.
// vs round 4 (278 us/dispatch, occupancy 23% = 8 waves/CU, all pipes idle):
//   - Same RT=64 tile (weight L2 traffic stays at the 1.3 GB minimum) but
//     1024 threads / 16 waves per block, still 1 block/CU (LDS 133 KB)
//     -> 4 waves/SIMD, occupancy ~46%: latency hiding doubles.
//   - QKVR GEMM re-split: wave w<8 owns (Q,K) cols [w*32,w*32+32);
//     wave w>=8 owns (V,R) same slices. acc = 64 VGPR/thread, fits the
//     128-VGPR cap required by 4 waves/SIMD (__launch_bounds__(1024,4)).
//   - Attention uses all 1024 threads: (row, head, half): each thread does a
//     16-dim half dot, combined with one __shfl_xor(1). Each thread writes AO
//     exactly over the Q bytes it alone read -> scores->PV barrier removed.
//   - Wo fragments prefetched into registers (8 x bf16x8 = 32 VGPR) right
//     after the QKVR epilogue barrier; L2 latency hides under attention VALU;
//     Wo GEMM has zero global loads.
// K0 (weight fp32->bf16 conversion) unchanged.

#define D_DIM   256
#define H_NUM   8
#define DH      32
#define RT      64
#define NTHR    1024
#define ROWS_TOT 131072
#define Y_SZ    33554432          // 131072*256
#define SCALE_F 0.17677669529663687f
#define W_ELEMS 65536             // 256*256 per matrix
#define WS_NEED (5 * W_ELEMS * 2) // bytes for bf16 weight copy

#define SX_LD   264   // shorts
#define SQK_LD  776   // shorts per row: [Q/AO 0..255 | K 256..511 | Veff 512..767 | pad]
#define KOFF    256
#define VOFF    512
#define SY_LD   260   // floats (aliases sQK storage)

typedef __attribute__((ext_vector_type(8))) short bf16x8;
typedef __attribute__((ext_vector_type(4))) float f32x4;

__device__ __forceinline__ float b2f(uint16_t s) {
    union { uint32_t u; float f; } c; c.u = ((uint32_t)s) << 16; return c.f;
}
__device__ __forceinline__ uint16_t f2b(float f) {
    union { float f; uint32_t u; } c; c.f = f;
    return (uint16_t)((c.u + 0x7fffu + ((c.u >> 16) & 1u)) >> 16);
}
__device__ __forceinline__ bf16x8 cvt8(const float* p) {
    const float4 a = *(const float4*)p;
    const float4 b = *(const float4*)(p + 4);
    bf16x8 r;
    r[0] = (short)f2b(a.x); r[1] = (short)f2b(a.y);
    r[2] = (short)f2b(a.z); r[3] = (short)f2b(a.w);
    r[4] = (short)f2b(b.x); r[5] = (short)f2b(b.y);
    r[6] = (short)f2b(b.z); r[7] = (short)f2b(b.w);
    return r;
}

// ---------------- K0: weight fp32 -> bf16 conversion ----------------
__global__ __launch_bounds__(256)
void conv_weights(const float* __restrict__ Wq, const float* __restrict__ Wk,
                  const float* __restrict__ Wv, const float* __restrict__ Wr,
                  const float* __restrict__ Wo, uint16_t* __restrict__ dst)
{
    const int m = blockIdx.x >> 6;                 // matrix id 0..4
    const float* src = (m == 0) ? Wq : (m == 1) ? Wk : (m == 2) ? Wv
                     : (m == 3) ? Wr : Wo;
    const int base = (blockIdx.x & 63) * 1024 + threadIdx.x * 4;
    const float4 v = *(const float4*)&src[base];
    uint2 pk;
    pk.x = (uint32_t)f2b(v.x) | ((uint32_t)f2b(v.y) << 16);
    pk.y = (uint32_t)f2b(v.z) | ((uint32_t)f2b(v.w) << 16);
    *(uint2*)&dst[(size_t)m * W_ELEMS + base] = pk;
}

// ---------------- K1: fused layer ----------------
template<bool WBF16>
__global__ __launch_bounds__(NTHR, 4)
void cmaa_fused(const float* __restrict__ tok,
                const float* __restrict__ Wq, const float* __restrict__ Wk,
                const float* __restrict__ Wv, const float* __restrict__ Wr,
                const float* __restrict__ Wo,
                const uint16_t* __restrict__ wbf,
                const float* __restrict__ lng, const float* __restrict__ lnb,
                float* __restrict__ outp)
{
    __shared__ __align__(16) uint16_t sX [RT * SX_LD];    // 33792 B
    __shared__ __align__(16) uint16_t sQK[RT * SQK_LD];   // 99328 B; also sY fp32

    const int tid  = threadIdx.x;
    const int wv   = tid >> 6;        // wave 0..15
    const int lane = tid & 63;
    const int l15  = lane & 15;
    const int quad = lane >> 4;
    const int R0   = blockIdx.x * RT;

    // ---------------- stage 0: X tile -> LDS (bf16) ----------------
    {
        const float* g = tok + (size_t)R0 * D_DIM;
        #pragma unroll
        for (int t = tid; t < RT * (D_DIM / 8); t += NTHR) {
            const int row = t >> 5, c = t & 31;
            *(bf16x8*)&sX[row * SX_LD + c * 8] = cvt8(&g[row * D_DIM + c * 8]);
        }
    }
    __syncthreads();

    // ---------------- QKVR GEMM ----------------
    // waves 0..7:  Q (acc[0]) and K (acc[1]), col slice wv*32 .. +32
    // waves 8..15: V (acc[0]) and R (acc[1]), same col slices
    {
        const int  colbase = (wv & 7) * 32;
        const bool qk = (wv < 8);
        const float*    WF0 = qk ? Wq : Wv;
        const float*    WF1 = qk ? Wk : Wr;
        const uint16_t* WB0 = wbf + (size_t)(qk ? 0 : 2) * W_ELEMS;
        const uint16_t* WB1 = WB0 + W_ELEMS;

        f32x4 acc[2][4][2];
        #pragma unroll
        for (int m = 0; m < 2; ++m)
            #pragma unroll
            for (int mt = 0; mt < 4; ++mt)
                #pragma unroll
                for (int nt = 0; nt < 2; ++nt)
                    acc[m][mt][nt] = (f32x4){0.f, 0.f, 0.f, 0.f};

        #pragma unroll
        for (int kk = 0; kk < 8; ++kk) {
            const int k0 = kk * 32;
            bf16x8 a[4];
            #pragma unroll
            for (int mt = 0; mt < 4; ++mt)
                a[mt] = *(const bf16x8*)&sX[(mt * 16 + l15) * SX_LD + k0 + quad * 8];

            bf16x8 b0[2], b1[2];
            #pragma unroll
            for (int nt = 0; nt < 2; ++nt) {
                const int wrow = colbase + nt * 16 + l15;
                if constexpr (WBF16) {
                    b0[nt] = *(const bf16x8*)&WB0[(size_t)wrow * D_DIM + k0 + quad * 8];
                    b1[nt] = *(const bf16x8*)&WB1[(size_t)wrow * D_DIM + k0 + quad * 8];
                } else {
                    b0[nt] = cvt8(&WF0[(size_t)wrow * D_DIM + k0 + quad * 8]);
                    b1[nt] = cvt8(&WF1[(size_t)wrow * D_DIM + k0 + quad * 8]);
                }
            }
            #pragma unroll
            for (int nt = 0; nt < 2; ++nt)
                #pragma unroll
                for (int mt = 0; mt < 4; ++mt)
                    acc[0][mt][nt] = __builtin_amdgcn_mfma_f32_16x16x32_bf16(a[mt], b0[nt], acc[0][mt][nt], 0, 0, 0);
            #pragma unroll
            for (int nt = 0; nt < 2; ++nt)
                #pragma unroll
                for (int mt = 0; mt < 4; ++mt)
                    acc[1][mt][nt] = __builtin_amdgcn_mfma_f32_16x16x32_bf16(a[mt], b1[nt], acc[1][mt][nt], 0, 0, 0);
        }

        // epilogue. C layout: col=lane&15, row=quad*4+reg
        if (qk) {
            #pragma unroll
            for (int mt = 0; mt < 4; ++mt)
                #pragma unroll
                for (int nt = 0; nt < 2; ++nt)
                    #pragma unroll
                    for (int r = 0; r < 4; ++r) {
                        const int row = mt * 16 + quad * 4 + r;
                        const int col = colbase + nt * 16 + l15;
                        sQK[row * SQK_LD + col]        = f2b(acc[0][mt][nt][r]);   // Q
                        sQK[row * SQK_LD + KOFF + col] = f2b(acc[1][mt][nt][r]);   // K
                    }
        } else {
            #pragma unroll
            for (int mt = 0; mt < 4; ++mt)
                #pragma unroll
                for (int nt = 0; nt < 2; ++nt)
                    #pragma unroll
                    for (int r = 0; r < 4; ++r) {
                        const int row = mt * 16 + quad * 4 + r;
                        const int col = colbase + nt * 16 + l15;
                        const float vvv = acc[0][mt][nt][r];
                        const float rr  = acc[1][mt][nt][r];
                        const float sig = 1.f / (1.f + __expf(-rr));
                        sQK[row * SQK_LD + VOFF + col] = f2b(vvv * sig);           // V_eff
                    }
        }
    }
    __syncthreads();

    // ---------------- prefetch Wo slice into registers ----------------
    // wave wv owns output cols [wv*16, wv*16+16); latency hides under attention
    bf16x8 bw3[8];
    {
        const uint16_t* WoB = wbf + (size_t)4 * W_ELEMS;
        const int worow = wv * 16 + l15;
        #pragma unroll
        for (int kk = 0; kk < 8; ++kk) {
            if constexpr (WBF16)
                bw3[kk] = *(const bf16x8*)&WoB[(size_t)worow * D_DIM + kk * 32 + quad * 8];
            else
                bw3[kk] = cvt8(&Wo[(size_t)worow * D_DIM + kk * 32 + quad * 8]);
        }
    }

    // ---------------- attention: 1024 thr = 64 rows x 8 heads x 2 halves ----
    {
        const int r    = tid >> 4;
        const int h    = (tid >> 1) & 7;
        const int half = tid & 1;
        const int gr = R0 + r;
        const int i  = r & 3;
        const int rb = r & ~3;
        int rn[3];
        #pragma unroll
        for (int l = 0; l < 3; ++l) { const int jj = l + (l >= i); rn[l] = rb + jj; }
        const int qoff = h * DH + half * 16;

        float q[16];
        #pragma unroll
        for (int t = 0; t < 2; ++t) {
            const bf16x8 v = *(const bf16x8*)&sQK[r * SQK_LD + qoff + t * 8];
            #pragma unroll
            for (int j = 0; j < 8; ++j) q[t * 8 + j] = b2f((uint16_t)v[j]);
        }

        float sc[3];
        #pragma unroll
        for (int l = 0; l < 3; ++l) {
            float s = 0.f;
            #pragma unroll
            for (int t = 0; t < 2; ++t) {
                const bf16x8 v = *(const bf16x8*)&sQK[rn[l] * SQK_LD + KOFF + qoff + t * 8];
                #pragma unroll
                for (int j = 0; j < 8; ++j) s += q[t * 8 + j] * b2f((uint16_t)v[j]);
            }
            s += __shfl_xor(s, 1);          // combine the two 16-dim halves
            sc[l] = s * SCALE_F;
        }
        const float mx = fmaxf(sc[0], fmaxf(sc[1], sc[2]));
        const float e0 = __expf(sc[0] - mx), e1 = __expf(sc[1] - mx), e2 = __expf(sc[2] - mx);
        const float inv = 1.f / (e0 + e1 + e2);
        const float al[3] = { e0 * inv, e1 * inv, e2 * inv };

        if (half == 0) {
            float* ap = outp + Y_SZ + ((size_t)gr * H_NUM + h) * 3;
            ap[0] = al[0]; ap[1] = al[1]; ap[2] = al[2];
        }

        // PV: each thread overwrites exactly the Q bytes it alone read -> no barrier
        #pragma unroll
        for (int t = 0; t < 2; ++t) {
            float o[8] = {0.f,0.f,0.f,0.f,0.f,0.f,0.f,0.f};
            #pragma unroll
            for (int l = 0; l < 3; ++l) {
                const bf16x8 vv = *(const bf16x8*)&sQK[rn[l] * SQK_LD + VOFF + qoff + t * 8];
                #pragma unroll
                for (int j = 0; j < 8; ++j) o[j] += al[l] * b2f((uint16_t)vv[j]);
            }
            bf16x8 pk;
            #pragma unroll
            for (int j = 0; j < 8; ++j) pk[j] = (short)f2b(o[j]);
            *(bf16x8*)&sQK[r * SQK_LD + qoff + t * 8] = pk;   // AO over dead Q
        }
    }
    __syncthreads();

    // ---------------- AO @ Wo^T (weights already in regs) + residual ----------
    {
        f32x4 acc3[4];
        #pragma unroll
        for (int mt = 0; mt < 4; ++mt) acc3[mt] = (f32x4){0.f, 0.f, 0.f, 0.f};

        #pragma unroll
        for (int kk = 0; kk < 8; ++kk) {
            const int k0 = kk * 32;
            bf16x8 a[4];
            #pragma unroll
            for (int mt = 0; mt < 4; ++mt)
                a[mt] = *(const bf16x8*)&sQK[(mt * 16 + l15) * SQK_LD + k0 + quad * 8];
            #pragma unroll
            for (int mt = 0; mt < 4; ++mt)
                acc3[mt] = __builtin_amdgcn_mfma_f32_16x16x32_bf16(a[mt], bw3[kk], acc3[mt], 0, 0, 0);
        }
        __syncthreads();   // all AO reads done before sY aliases sQK

        float* sY = (float*)sQK;
        #pragma unroll
        for (int mt = 0; mt < 4; ++mt)
            #pragma unroll
            for (int r = 0; r < 4; ++r) {
                const int row = mt * 16 + quad * 4 + r;
                const int col = wv * 16 + l15;
                sY[row * SY_LD + col] = acc3[mt][r] + b2f(sX[row * SX_LD + col]);
            }
    }
    __syncthreads();

    // ---------------- two-pass LayerNorm + store y ----------------
    {
        const float* sY = (const float*)sQK;
        const int row = tid >> 4;   // 64 rows x 16 lanes
        const int sub = tid & 15;
        float vals[16];
        float s = 0.f;
        #pragma unroll
        for (int j = 0; j < 4; ++j) {
            const float4 v = *(const float4*)&sY[row * SY_LD + j * 64 + sub * 4];
            vals[j*4+0] = v.x; vals[j*4+1] = v.y; vals[j*4+2] = v.z; vals[j*4+3] = v.w;
            s += v.x + v.y + v.z + v.w;
        }
        s += __shfl_xor(s, 1); s += __shfl_xor(s, 2);
        s += __shfl_xor(s, 4); s += __shfl_xor(s, 8);
        const float mean = s * (1.f / 256.f);
        float s2 = 0.f;
        #pragma unroll
        for (int j = 0; j < 16; ++j) { const float d = vals[j] - mean; s2 += d * d; }
        s2 += __shfl_xor(s2, 1); s2 += __shfl_xor(s2, 2);
        s2 += __shfl_xor(s2, 4); s2 += __shfl_xor(s2, 8);
        const float var  = fmaxf(s2 * (1.f / 256.f), 0.f);
        const float rstd = rsqrtf(var + 1e-5f);

        float* orow = outp + (size_t)(R0 + row) * D_DIM;
        #pragma unroll
        for (int j = 0; j < 4; ++j) {
            const int col = j * 64 + sub * 4;
            const float4 g4 = *(const float4*)&lng[col];
            const float4 b4 = *(const float4*)&lnb[col];
            float4 o4;
            o4.x = (vals[j*4+0] - mean) * rstd * g4.x + b4.x;
            o4.y = (vals[j*4+1] - mean) * rstd * g4.y + b4.y;
            o4.z = (vals[j*4+2] - mean) * rstd * g4.z + b4.z;
            o4.w = (vals[j*4+3] - mean) * rstd * g4.w + b4.w;
            *(float4*)&orow[col] = o4;
        }
    }
}

extern "C" void kernel_launch(void* const* d_in, const int* in_sizes, int n_in,
                              void* d_out, int out_size, void* d_ws, size_t ws_size,
                              hipStream_t stream) {
    (void)in_sizes; (void)n_in; (void)out_size;
    const float* tok = (const float*)d_in[0];
    const float* Wq  = (const float*)d_in[1];
    const float* Wk  = (const float*)d_in[2];
    const float* Wv  = (const float*)d_in[3];
    const float* Wr  = (const float*)d_in[4];
    const float* Wo  = (const float*)d_in[5];
    const float* lng = (const float*)d_in[6];
    const float* lnb = (const float*)d_in[7];
    float* outp = (float*)d_out;
    uint16_t* wbf = (uint16_t*)d_ws;

    dim3 grid(ROWS_TOT / RT), block(NTHR);
    if (ws_size >= (size_t)WS_NEED) {
        conv_weights<<<dim3(320), dim3(256), 0, stream>>>(Wq, Wk, Wv, Wr, Wo, wbf);
        cmaa_fused<true><<<grid, block, 0, stream>>>(
            tok, Wq, Wk, Wv, Wr, Wo, wbf, lng, lnb, outp);
    } else {
        cmaa_fused<false><<<grid, block, 0, stream>>>(
            tok, Wq, Wk, Wv, Wr, Wo, wbf, lng, lnb, outp);
    }
}